// Round 1
// baseline (400.106 us; speedup 1.0000x reference)
//
#include <hip/hip_runtime.h>
#include <hip/hip_bf16.h>
#include <cmath>

// Problem constants (ShadowFreeTernaryLinear): out = softplus(log_scale)·(x·state^T) + bias
#define B_SZ   32
#define K_SZ   8192
#define N_SZ   8192
#define WAVES  8                 // waves per block = K-split factor
#define BLOCK  (WAVES * 64)      // 512 threads
#define NTILE  32                // output columns per block
#define KCHUNK (K_SZ / WAVES)    // 1024 K per wave

typedef __attribute__((ext_vector_type(8))) short bf16x8;   // MFMA A/B frag (8 bf16)
typedef __attribute__((ext_vector_type(4))) float f32x4;    // MFMA C/D frag

// fp32 -> bf16 (round-half-up via +0x8000), pack pair into one dword (lo in low 16)
__device__ __forceinline__ unsigned pack_rn(float lo, float hi) {
  unsigned ul = __builtin_bit_cast(unsigned, lo) + 0x8000u;
  unsigned uh = __builtin_bit_cast(unsigned, hi) + 0x8000u;
  return (ul >> 16) | (uh & 0xFFFF0000u);
}

// ternary int32 {-1,0,1} -> bf16 exactly (truncation of fp32 bits is exact here)
__device__ __forceinline__ unsigned pack_w(int w0, int w1) {
  unsigned u0 = __builtin_bit_cast(unsigned, (float)w0);
  unsigned u1 = __builtin_bit_cast(unsigned, (float)w1);
  return (u0 >> 16) | (u1 & 0xFFFF0000u);
}

__device__ __forceinline__ bf16x8 afrag(float4 a, float4 b) {
  union { unsigned u[4]; bf16x8 v; } t;
  t.u[0] = pack_rn(a.x, a.y);
  t.u[1] = pack_rn(a.z, a.w);
  t.u[2] = pack_rn(b.x, b.y);
  t.u[3] = pack_rn(b.z, b.w);
  return t.v;
}

__device__ __forceinline__ bf16x8 bfrag(int4 a, int4 b) {
  union { unsigned u[4]; bf16x8 v; } t;
  t.u[0] = pack_w(a.x, a.y);
  t.u[1] = pack_w(a.z, a.w);
  t.u[2] = pack_w(b.x, b.y);
  t.u[3] = pack_w(b.z, b.w);
  return t.v;
}

__global__ __launch_bounds__(BLOCK, 2) void ternary_mm(
    const float* __restrict__ X,          // [32, 8192] fp32
    const float* __restrict__ log_scale,  // [8192]
    const float* __restrict__ bias,       // [8192]
    const int*   __restrict__ W,          // [8192, 8192] ternary int32, row-major [out,in]
    float*       __restrict__ out)        // [32, 8192] fp32
{
  // k-split partials: [wave][batch 32][ntile 32(+1 pad)]
  __shared__ float red[WAVES][B_SZ][NTILE + 1];

  const int tid  = threadIdx.x;
  const int wv   = tid >> 6;     // wave id 0..7 -> K chunk
  const int lane = tid & 63;
  const int q    = lane >> 4;    // quad 0..3
  const int r    = lane & 15;    // row within fragment
  const int nbase = blockIdx.x * NTILE;
  const int kbase = wv * KCHUNK + q * 8;

  // A frag source: x rows r (m-tile 0) and r+16 (m-tile 1), k contiguous
  const float* xp0 = X + (size_t)r        * K_SZ + kbase;
  const float* xp1 = X + (size_t)(r + 16) * K_SZ + kbase;
  // B frag source: W rows nbase+r (n-tile 0), nbase+16+r (n-tile 1), k contiguous
  const int* wp0 = W + (size_t)(nbase + r)      * K_SZ + kbase;
  const int* wp1 = W + (size_t)(nbase + 16 + r) * K_SZ + kbase;

  f32x4 acc00 = {0.f,0.f,0.f,0.f}, acc01 = {0.f,0.f,0.f,0.f};
  f32x4 acc10 = {0.f,0.f,0.f,0.f}, acc11 = {0.f,0.f,0.f,0.f};

  #pragma unroll 2
  for (int kb = 0; kb < KCHUNK; kb += 32) {
    float4 a0l = *(const float4*)(xp0 + kb);
    float4 a0h = *(const float4*)(xp0 + kb + 4);
    float4 a1l = *(const float4*)(xp1 + kb);
    float4 a1h = *(const float4*)(xp1 + kb + 4);
    int4   b0l = *(const int4*)(wp0 + kb);
    int4   b0h = *(const int4*)(wp0 + kb + 4);
    int4   b1l = *(const int4*)(wp1 + kb);
    int4   b1h = *(const int4*)(wp1 + kb + 4);

    bf16x8 A0 = afrag(a0l, a0h);
    bf16x8 A1 = afrag(a1l, a1h);
    bf16x8 B0 = bfrag(b0l, b0h);
    bf16x8 B1 = bfrag(b1l, b1h);

    acc00 = __builtin_amdgcn_mfma_f32_16x16x32_bf16(A0, B0, acc00, 0, 0, 0);
    acc01 = __builtin_amdgcn_mfma_f32_16x16x32_bf16(A0, B1, acc01, 0, 0, 0);
    acc10 = __builtin_amdgcn_mfma_f32_16x16x32_bf16(A1, B0, acc10, 0, 0, 0);
    acc11 = __builtin_amdgcn_mfma_f32_16x16x32_bf16(A1, B1, acc11, 0, 0, 0);
  }

  // C/D layout (m89-verified): col = lane&15, row = (lane>>4)*4 + reg
  #pragma unroll
  for (int rg = 0; rg < 4; ++rg) {
    red[wv][q * 4 + rg     ][r     ] = acc00[rg];
    red[wv][q * 4 + rg     ][16 + r] = acc01[rg];
    red[wv][16 + q * 4 + rg][r     ] = acc10[rg];
    red[wv][16 + q * 4 + rg][16 + r] = acc11[rg];
  }
  __syncthreads();

  // Reduce 8 k-split partials; 1024 outputs / 512 threads = 2 each.
  #pragma unroll
  for (int e = 0; e < 2; ++e) {
    int oidx = tid + e * BLOCK;
    int b  = oidx >> 5;        // batch row 0..31
    int nl = oidx & 31;        // column within tile
    float s = 0.f;
    #pragma unroll
    for (int w8 = 0; w8 < WAVES; ++w8) s += red[w8][b][nl];
    int o = nbase + nl;
    float sp    = log1pf(expf(log_scale[o]));   // softplus; z ≈ -4.5, no overflow risk
    float scale = fmaxf(sp, 1e-4f);
    out[(size_t)b * N_SZ + o] = s * scale + bias[o];
  }
}

extern "C" void kernel_launch(void* const* d_in, const int* in_sizes, int n_in,
                              void* d_out, int out_size, void* d_ws, size_t ws_size,
                              hipStream_t stream) {
  const float* X  = (const float*)d_in[0];   // inputs [32,8192] fp32
  const float* ls = (const float*)d_in[1];   // log_scale [8192] fp32
  const float* bs = (const float*)d_in[2];   // bias [8192] fp32
  const int*   W  = (const int*)d_in[3];     // weight_state [8192,8192] int32
  float* out = (float*)d_out;
  ternary_mm<<<N_SZ / NTILE, BLOCK, 0, stream>>>(X, ls, bs, W, out);
}

// Round 2
// 366.335 us; speedup vs baseline: 1.0922x; 1.0922x over previous
//
#include <hip/hip_runtime.h>
#include <hip/hip_bf16.h>
#include <cmath>

// out[b,o] = max(softplus(log_scale[o]),1e-4) * sum_k x[b,k]*W[o,k] + bias[o]
// B=32, K=N=8192. W ternary int32 [N,K] row-major. Memory-bound on W (256 MB/launch).

#define K_SZ   8192
#define N_SZ   8192
#define B_SZ   32
#define KSPLIT 2
#define KHALF  (K_SZ / KSPLIT)   // 4096
#define BN     32                // output cols per block
#define BK     128               // K ints per staged step
#define STEPS  (KHALF / BK)      // 32
#define LDW    132               // padded LDS row stride in ints (132 = 4*33, int4-aligned)

typedef __attribute__((ext_vector_type(8))) short bf16x8;   // MFMA A/B frag
typedef __attribute__((ext_vector_type(4))) float f32x4;    // MFMA C/D frag

// fp32 pair -> packed bf16 (round-half-up), lo in low 16
__device__ __forceinline__ unsigned pack_rn(float lo, float hi) {
  unsigned ul = __builtin_bit_cast(unsigned, lo) + 0x8000u;
  unsigned uh = __builtin_bit_cast(unsigned, hi) + 0x8000u;
  return (ul >> 16) | (uh & 0xFFFF0000u);
}
// ternary int pair -> packed bf16 (exact)
__device__ __forceinline__ unsigned pack_w(int w0, int w1) {
  unsigned u0 = __builtin_bit_cast(unsigned, (float)w0);
  unsigned u1 = __builtin_bit_cast(unsigned, (float)w1);
  return (u0 >> 16) | (u1 & 0xFFFF0000u);
}

// Rearrange X fp32[32,8192] -> Xr bf16 chunks in MFMA A-frag order.
// Chunk c = kb*2 + mt (kb = 32-k block 0..255, mt = m-tile 0..1): 1 KB where
// lane l holds X[mt*16 + (l&15)][kb*32 + (l>>4)*8 .. +8] as bf16x8.
__global__ void xprep(const float* __restrict__ X, uint4* __restrict__ Xr) {
  int t = blockIdx.x * blockDim.x + threadIdx.x;   // 0..32767
  int lane = t & 63;
  int chunk = t >> 6;                              // 0..511
  int kb = chunk >> 1;
  int mt = chunk & 1;
  int row = mt * 16 + (lane & 15);
  int k0 = kb * 32 + (lane >> 4) * 8;
  const float* p = X + (size_t)row * K_SZ + k0;
  float4 a = *(const float4*)p;
  float4 b = *(const float4*)(p + 4);
  uint4 o;
  o.x = pack_rn(a.x, a.y); o.y = pack_rn(a.z, a.w);
  o.z = pack_rn(b.x, b.y); o.w = pack_rn(b.z, b.w);
  Xr[t] = o;   // coalesced
}

__global__ __launch_bounds__(256, 2) void tmm(
    const int*   __restrict__ W,
    const uint4* __restrict__ Xr,
    const float* __restrict__ log_scale,
    const float* __restrict__ bias,
    float*       __restrict__ out) {
  __shared__ int lds[32 * LDW];   // 16,896 B -> 2 blocks/CU easily

  const int tid  = threadIdx.x;
  const int w    = tid >> 6;       // wave 0..3
  const int lane = tid & 63;
  const int q    = lane >> 4;
  const int r    = lane & 15;
  const int nb   = blockIdx.x * BN;
  const int kh   = blockIdx.y;     // k-half
  const int mt   = w & 1;          // wave's m-tile (batch 16-group)
  const int nt   = w >> 1;         // wave's n-tile

  // --- W staging addresses: wave w stages rows 8w..8w+7, 4 issues x 2 rows.
  // Lane-contiguous: lanes 0..31 -> row (8w+2i), ints 4*(l&31); lanes 32..63 -> row+1.
  const int srow = 8 * w + (lane >> 5);
  const int skof = 4 * (lane & 31);
  const int* gW = W + (size_t)(nb + srow) * K_SZ + (size_t)kh * KHALF + skof;
  const int lof = srow * LDW + skof;

  // prologue: load step 0 W regs
  int4 wr0 = *(const int4*)(gW + 0 * 2 * K_SZ);
  int4 wr1 = *(const int4*)(gW + 1 * 2 * K_SZ);
  int4 wr2 = *(const int4*)(gW + 2 * 2 * K_SZ);
  int4 wr3 = *(const int4*)(gW + 3 * 2 * K_SZ);

  // prologue: A frags for step 0 (contiguous 1 KB wave-loads, L2-hot)
  const uint4* xr = Xr + lane;
  const int kbb = kh * (KHALF / 32);     // base 32-k block index
  uint4 a0 = xr[(size_t)((kbb + 0) * 2 + mt) * 64];
  uint4 a1 = xr[(size_t)((kbb + 1) * 2 + mt) * 64];
  uint4 a2 = xr[(size_t)((kbb + 2) * 2 + mt) * 64];
  uint4 a3 = xr[(size_t)((kbb + 3) * 2 + mt) * 64];

  f32x4 acc = {0.f, 0.f, 0.f, 0.f};
  const int Rbase = (nt * 16 + r) * LDW;

  for (int step = 0; step < STEPS; ++step) {
    __syncthreads();                       // prev step's LDS consumers done
    *(int4*)&lds[lof + 0 * 2 * LDW] = wr0;
    *(int4*)&lds[lof + 1 * 2 * LDW] = wr1;
    *(int4*)&lds[lof + 2 * 2 * LDW] = wr2;
    *(int4*)&lds[lof + 3 * 2 * LDW] = wr3;
    if (step + 1 < STEPS) {                // prefetch next W: in flight across compute
      const int* g = gW + (step + 1) * BK;
      wr0 = *(const int4*)(g + 0 * 2 * K_SZ);
      wr1 = *(const int4*)(g + 1 * 2 * K_SZ);
      wr2 = *(const int4*)(g + 2 * 2 * K_SZ);
      wr3 = *(const int4*)(g + 3 * 2 * K_SZ);
    }
    __syncthreads();                       // LDS writes visible

    uint4 ca0 = a0, ca1 = a1, ca2 = a2, ca3 = a3;
    if (step + 1 < STEPS) {                // prefetch next A frags
      int kb2 = kbb + (step + 1) * 4;
      a0 = xr[(size_t)((kb2 + 0) * 2 + mt) * 64];
      a1 = xr[(size_t)((kb2 + 1) * 2 + mt) * 64];
      a2 = xr[(size_t)((kb2 + 2) * 2 + mt) * 64];
      a3 = xr[(size_t)((kb2 + 3) * 2 + mt) * 64];
    }

    #pragma unroll
    for (int s = 0; s < 4; ++s) {
      uint4 ca = (s == 0) ? ca0 : (s == 1) ? ca1 : (s == 2) ? ca2 : ca3;
      int ro = Rbase + s * 32 + q * 8;
      int4 b0 = *(const int4*)&lds[ro];
      int4 b1 = *(const int4*)&lds[ro + 4];
      union { unsigned u[4]; bf16x8 v; } Bf;
      Bf.u[0] = pack_w(b0.x, b0.y); Bf.u[1] = pack_w(b0.z, b0.w);
      Bf.u[2] = pack_w(b1.x, b1.y); Bf.u[3] = pack_w(b1.z, b1.w);
      bf16x8 Af = __builtin_bit_cast(bf16x8, ca);
      acc = __builtin_amdgcn_mfma_f32_16x16x32_bf16(Af, Bf.v, acc, 0, 0, 0);
    }
  }

  // epilogue: scale + bias, k-split combine via atomics (2-way, order-independent)
  const int o = nb + nt * 16 + r;
  float sp    = log1pf(expf(log_scale[o]));
  float scale = fmaxf(sp, 1e-4f);
  float badd  = (kh == 0) ? bias[o] : 0.f;
  #pragma unroll
  for (int rg = 0; rg < 4; ++rg) {
    int b = mt * 16 + q * 4 + rg;   // C/D layout: row=(lane>>4)*4+reg -> batch, col=lane&15 -> o
    atomicAdd(&out[(size_t)b * N_SZ + o], acc[rg] * scale + badd);
  }
}

extern "C" void kernel_launch(void* const* d_in, const int* in_sizes, int n_in,
                              void* d_out, int out_size, void* d_ws, size_t ws_size,
                              hipStream_t stream) {
  const float* X  = (const float*)d_in[0];
  const float* ls = (const float*)d_in[1];
  const float* bs = (const float*)d_in[2];
  const int*   W  = (const int*)d_in[3];
  float* out = (float*)d_out;
  uint4* Xr = (uint4*)d_ws;   // 512 KB

  hipMemsetAsync(out, 0, (size_t)B_SZ * N_SZ * sizeof(float), stream);
  xprep<<<128, 256, 0, stream>>>(X, Xr);
  dim3 grid(N_SZ / BN, KSPLIT);
  tmm<<<grid, 256, 0, stream>>>(W, Xr, ls, bs, out);
}